// Round 5
// baseline (5688.419 us; speedup 1.0000x reference)
//
#include <hip/hip_runtime.h>

#define SEQ   512
#define BATCH 64
#define D_IN  1024
#define D_LAT 1024
#define D_CAT 2048
#define NBLK  128      // j-blocks; each owns 8 output columns (j) x 4 gates = 32 W rows
#define JPB   8
#define ROWS  32
#define THREADS 512    // 8 waves: all own a 128-wide h-chunk; waves 4-7 also own a 256-wide x-chunk
#define GPS   67       // partial-gates batch stride: 67 = 3 dwords mod 32 -> <=3-way bank alias

typedef unsigned short u16;
typedef __attribute__((ext_vector_type(8))) short short8;   // bf16x8 MFMA frag (4 VGPRs)
typedef __attribute__((ext_vector_type(4))) float floatx4;  // fp32x4 accumulator

__device__ __forceinline__ u16 f2bf(float f) {
    union { float f; unsigned u; } a; a.f = f;
    unsigned u = a.u;
    return (u16)((u + 0x7FFFu + ((u >> 16) & 1u)) >> 16);   // RNE
}

__device__ __forceinline__ float sigm(float x)  { return 1.0f / (1.0f + __expf(-x)); }
__device__ __forceinline__ float tanhf_(float x){ return 2.0f / (1.0f + __expf(-2.0f * x)) - 1.0f; }

__global__ void cvt_bf16(const float* __restrict__ x, u16* __restrict__ xb, int n8) {
    int i = blockIdx.x * blockDim.x + threadIdx.x;
    int stride = gridDim.x * blockDim.x;
    for (; i < n8; i += stride) {
        float4 v0 = ((const float4*)x)[2 * i];
        float4 v1 = ((const float4*)x)[2 * i + 1];
        short8 o;
        o[0] = (short)f2bf(v0.x); o[1] = (short)f2bf(v0.y);
        o[2] = (short)f2bf(v0.z); o[3] = (short)f2bf(v0.w);
        o[4] = (short)f2bf(v1.x); o[5] = (short)f2bf(v1.y);
        o[6] = (short)f2bf(v1.z); o[7] = (short)f2bf(v1.w);
        *(short8*)(xb + 8 * (size_t)i) = o;
    }
}

// Readiness protocol: slots[j] = t+1 published by block j's wave 0, lane 0.
// ALL of block j's h-bits for step t+1 are stored by wave 0 itself (2 x 8B
// agent-scope sc1 write-through stores per lane, packed from LDS hstage);
// wave 0 drains them with s_waitcnt vmcnt(0) (per-wave counter covers all 64
// lanes) and THEN lane 0 stores the tag. So every h-store is at the coherence
// point before slots[j] flips. Consumer wave c (h-cols [128c,128c+128)) needs
// blocks 16c..16c+15: lane l polls slots[16c + (l&15)] with agent-scope loads
// (proven to observe remote-XCD stores). Tags monotonic -> no reset race.
// h addresses are fresh each step -> no stale cached copies.

__launch_bounds__(THREADS, 2)
__global__ void lstm_persist(const float* __restrict__ Wf, const float* __restrict__ bfp,
                             const float* __restrict__ Wi, const float* __restrict__ bip,
                             const float* __restrict__ Wo, const float* __restrict__ bop,
                             const float* __restrict__ Wc, const float* __restrict__ bcp,
                             const u16* __restrict__ xb,     // [SEQ*BATCH*D_IN] bf16
                             u16* __restrict__ hhist,        // [(SEQ+1)*BATCH*D_LAT] bf16
                             float* __restrict__ out,        // [SEQ*BATCH*D_LAT]
                             unsigned* __restrict__ slots) { // [NBLK] readiness slots
    __shared__ __align__(16) float gp[8][ROWS][GPS];         // 68608 B
    __shared__ __align__(16) u16 hstage[8][72];              // 1152 B (pad 72 -> 2-way max)
    __shared__ float biasL[ROWS];

    const int tid  = threadIdx.x;
    const int jblk = blockIdx.x;
    const int c    = tid >> 6;          // wave id: h-chunk 0..7; waves 4-7 also x-chunk c-4
    const int lane = tid & 63;
    const int m    = lane & 15;         // W-row-in-tile (B n-index) == C col
    const int q    = lane >> 4;         // k-quad within k-step

    // ---- one-time: weight fragments -> registers ----
    // All waves: bregH = h-part cols [c*128, c*128+128)          (2 rt x 4 ks = 32 VGPR)
    // Waves 4-7: bregX = x-part cols [(c-4)*256, (c-4)*256+256)  (2 rt x 8 ks = 64 VGPR)
    short8 bregH[2][4];
    short8 bregX[2][8];
    #pragma unroll
    for (int rt = 0; rt < 2; ++rt) {
        const int rr  = rt * 16 + m;            // 0..31: gate g = rr>>3, j-in-block = rr&7
        const int g   = rr >> 3;
        const int jj2 = rr & 7;
        const float* Wg = (g == 0) ? Wf : (g == 1) ? Wi : (g == 2) ? Wo : Wc;
        const float* rowp = Wg + (size_t)(jblk * JPB + jj2) * D_CAT;
        #pragma unroll
        for (int ks = 0; ks < 4; ++ks) {
            const float* ph = rowp + c * 128 + ks * 32 + q * 8;          // h cols
            float4 h0 = *(const float4*)(ph);
            float4 h1 = *(const float4*)(ph + 4);
            short8 bh;
            bh[0] = (short)f2bf(h0.x); bh[1] = (short)f2bf(h0.y);
            bh[2] = (short)f2bf(h0.z); bh[3] = (short)f2bf(h0.w);
            bh[4] = (short)f2bf(h1.x); bh[5] = (short)f2bf(h1.y);
            bh[6] = (short)f2bf(h1.z); bh[7] = (short)f2bf(h1.w);
            bregH[rt][ks] = bh;
        }
        if (c >= 4) {
            #pragma unroll
            for (int ks = 0; ks < 8; ++ks) {
                const float* px = rowp + 1024 + (c - 4) * 256 + ks * 32 + q * 8;
                float4 x0 = *(const float4*)(px);
                float4 x1 = *(const float4*)(px + 4);
                short8 bx;
                bx[0] = (short)f2bf(x0.x); bx[1] = (short)f2bf(x0.y);
                bx[2] = (short)f2bf(x0.z); bx[3] = (short)f2bf(x0.w);
                bx[4] = (short)f2bf(x1.x); bx[5] = (short)f2bf(x1.y);
                bx[6] = (short)f2bf(x1.z); bx[7] = (short)f2bf(x1.w);
                bregX[rt][ks] = bx;
            }
        }
    }
    if (tid < ROWS) {
        const float* bsrc = (tid < 8) ? bfp : (tid < 16) ? bip : (tid < 24) ? bop : bcp;
        biasL[tid] = bsrc[jblk * JPB + (tid & 7)];
    }
    __syncthreads();

    // combine mapping: ALL 512 threads; wave c handles gate column jj == c,
    // lane == batch b. One c-state register per thread.
    float creg = 0.0f;

    floatx4 acc[2][4];
    #pragma unroll
    for (int rt = 0; rt < 2; ++rt)
        #pragma unroll
        for (int bt = 0; bt < 4; ++bt)
            acc[rt][bt] = (floatx4){0.f, 0.f, 0.f, 0.f};

    // prologue: waves 4-7 compute x(0) contribution
    if (c >= 4) {
        const u16* xptr = xb + (size_t)(c - 4) * 256 + q * 8;
        #pragma unroll
        for (int ks = 0; ks < 8; ++ks)
            #pragma unroll
            for (int bt = 0; bt < 4; ++bt) {
                short8 a = *(const short8*)(xptr + (size_t)(bt * 16 + m) * 1024 + ks * 32);
                acc[0][bt] = __builtin_amdgcn_mfma_f32_16x16x32_bf16(a, bregX[0][ks], acc[0][bt], 0, 0, 0);
                acc[1][bt] = __builtin_amdgcn_mfma_f32_16x16x32_bf16(a, bregX[1][ks], acc[1][bt], 0, 0, 0);
            }
    }

    const unsigned* myslot = slots + 16 * c + (lane & 15);   // 4-lane redundant poll

    #pragma unroll 1
    for (int t = 0; t < SEQ; ++t) {
        // ===== per-wave wait: this wave's 16 h-producer blocks (16c..16c+15) =====
        for (;;) {
            unsigned v = __hip_atomic_load(myslot, __ATOMIC_RELAXED,
                                           __HIP_MEMORY_SCOPE_AGENT);
            if (__all((int)(v >= (unsigned)t))) break;
            __builtin_amdgcn_s_sleep(1);
        }
        asm volatile("" ::: "memory");   // keep h-loads below the readiness check

        // ===== h-chunk MFMA (critical path, all 8 waves) =====
        const u16* hptr = hhist + (size_t)t * (BATCH * D_LAT) + c * 128 + q * 8;
        #pragma unroll
        for (int ks = 0; ks < 4; ++ks)
            #pragma unroll
            for (int bt = 0; bt < 4; ++bt) {
                short8 a = *(const short8*)(hptr + (size_t)(bt * 16 + m) * 1024 + ks * 32);
                acc[0][bt] = __builtin_amdgcn_mfma_f32_16x16x32_bf16(a, bregH[0][ks], acc[0][bt], 0, 0, 0);
                acc[1][bt] = __builtin_amdgcn_mfma_f32_16x16x32_bf16(a, bregH[1][ks], acc[1][bt], 0, 0, 0);
            }

        // C-layout: n(row-in-tile)=lane&15, m(batch-in-tile)=q*4+reg
        #pragma unroll
        for (int rt = 0; rt < 2; ++rt)
            #pragma unroll
            for (int bt = 0; bt < 4; ++bt)
                #pragma unroll
                for (int r = 0; r < 4; ++r)
                    gp[c][rt * 16 + m][bt * 16 + q * 4 + r] = acc[rt][bt][r];
        // reset acc now (values safely stored); waves 4-7 accumulate x(t+1) below
        #pragma unroll
        for (int rt = 0; rt < 2; ++rt)
            #pragma unroll
            for (int bt = 0; bt < 4; ++bt)
                acc[rt][bt] = (floatx4){0.f, 0.f, 0.f, 0.f};
        __syncthreads();   // S1: gp complete

        // ===== combine: all 512 threads (jj = c, b = lane) =====
        float hf;
        {
            const int jj = c;
            const int b  = lane;
            float pf = biasL[jj], pi = biasL[8 + jj], po = biasL[16 + jj], pg = biasL[24 + jj];
            #pragma unroll
            for (int cc = 0; cc < 8; ++cc) {
                pf += gp[cc][jj][b];
                pi += gp[cc][8 + jj][b];
                po += gp[cc][16 + jj][b];
                pg += gp[cc][24 + jj][b];
            }
            float ft = sigm(pf), it = sigm(pi), ot = sigm(po), gt = tanhf_(pg);
            creg = ft * creg + it * gt;
            hf = ot * tanhf_(creg);
            hstage[jj][b] = f2bf(hf);
        }
        __syncthreads();   // S2: hstage complete

        // ===== wave 0: packed h publish (ONLY h-stores gate the tag) =====
        if (c == 0) {
            union { short8 s; unsigned long long u[2]; } pk;
            #pragma unroll
            for (int j = 0; j < 8; ++j) pk.s[j] = (short)hstage[j][lane];
            unsigned long long* hp = (unsigned long long*)
                (hhist + (size_t)(t + 1) * (BATCH * D_LAT) + (size_t)lane * D_LAT + jblk * JPB);
            __hip_atomic_store(&hp[0], pk.u[0], __ATOMIC_RELAXED, __HIP_MEMORY_SCOPE_AGENT);
            __hip_atomic_store(&hp[1], pk.u[1], __ATOMIC_RELAXED, __HIP_MEMORY_SCOPE_AGENT);
            // drain THIS wave's h-stores to the coherence point, then publish.
            asm volatile("s_waitcnt vmcnt(0)" ::: "memory");
            if (lane == 0) {
                __hip_atomic_store(&slots[jblk], (unsigned)(t + 1),
                                   __ATOMIC_RELAXED, __HIP_MEMORY_SCOPE_AGENT);
            }
        }

        // ===== out store (off the publish path) =====
        out[(size_t)t * (BATCH * D_LAT) + (size_t)lane * D_LAT + jblk * JPB + c] = hf;

        // ===== x(t+1) GEMM (waves 4-7): overlaps publish/propagate/detect =====
        if (c >= 4 && t + 1 < SEQ) {
            const u16* xptr = xb + (size_t)(t + 1) * (BATCH * D_IN) + (c - 4) * 256 + q * 8;
            #pragma unroll
            for (int ks = 0; ks < 8; ++ks)
                #pragma unroll
                for (int bt = 0; bt < 4; ++bt) {
                    short8 a = *(const short8*)(xptr + (size_t)(bt * 16 + m) * 1024 + ks * 32);
                    acc[0][bt] = __builtin_amdgcn_mfma_f32_16x16x32_bf16(a, bregX[0][ks], acc[0][bt], 0, 0, 0);
                    acc[1][bt] = __builtin_amdgcn_mfma_f32_16x16x32_bf16(a, bregX[1][ks], acc[1][bt], 0, 0, 0);
                }
        }
        // NOTE: no trailing __syncthreads needed: gp(t) was fully consumed by
        // combine before S2, and gp(t+1) writes happen only after each wave's
        // own poll (which requires all producers past their S2 publish).
        // hstage(t) is only read by wave 0 between S2(t) and its next poll;
        // hstage(t+1) writes happen after S1(t+1), which wave 0 must reach.
    }
}

extern "C" void kernel_launch(void* const* d_in, const int* in_sizes, int n_in,
                              void* d_out, int out_size, void* d_ws, size_t ws_size,
                              hipStream_t stream) {
    const float* x  = (const float*)d_in[0];
    const float* Wf = (const float*)d_in[1];
    const float* bf = (const float*)d_in[2];
    const float* Wi = (const float*)d_in[3];
    const float* bi = (const float*)d_in[4];
    const float* Wo = (const float*)d_in[5];
    const float* bo = (const float*)d_in[6];
    const float* Wc = (const float*)d_in[7];
    const float* bc = (const float*)d_in[8];
    float* out = (float*)d_out;

    char* ws = (char*)d_ws;
    unsigned* slots = (unsigned*)ws;                                     // 128 u32 = 512 B
    u16* hhist = (u16*)(ws + 1024);                                      // 513*64*1024*2 B
    u16* xb    = (u16*)(ws + 1024 + (size_t)(SEQ + 1) * BATCH * D_LAT * 2);

    // zero slots + h_hist[0] (contiguous region) -- layout byte-identical to
    // the proven rounds 0-2 (no workspace growth).
    hipMemsetAsync(ws, 0, 1024 + (size_t)BATCH * D_LAT * 2, stream);
    cvt_bf16<<<2048, 256, 0, stream>>>(x, xb, SEQ * BATCH * D_IN / 8);
    lstm_persist<<<NBLK, THREADS, 0, stream>>>(Wf, bf, Wi, bi, Wo, bo, Wc, bc,
                                               xb, hhist, out, slots);
}